// Round 4
// baseline (234.291 us; speedup 1.0000x reference)
//
#include <hip/hip_runtime.h>

// Single-head causal attention. B=4, T=4096, C=1024, H=64, fp32 io.
// scale = C**-0.5 = 1/32, folded with log2(e) into Wq (no-max softmax:
// scores*scale ~ N(0,0.25^2) -> exp2 of raw scores safe, fp16 P safe).
// R14: combine FUSED into attn_partial (last-chunk-reduces):
//  - per-(b,qt) device-scope counter (agent-scope fetch_add, release/acquire
//    fences -- partials span both XCDs of the batch pair, G16); the block
//    arriving last runs the 4-pass combine for its 128 rows. Overlaps all
//    combine work with still-running attn blocks and deletes the combine
//    launch + full-grid drain boundary.
//  - nc==1 groups (qt<=1) write out directly, skipping opart/ml.
//  - counters zeroed by wconv (stream-ordered ahead of attn).
//  - exp2f -> __builtin_amdgcn_exp2f (raw v_exp_f32; args bounded).
//      attn core loop = R11/R13 verbatim; qkv/wconv swizzles = R13.

#define BSZ 4
#define TSZ 4096
#define CSZ 1024
#define MSZ (BSZ * TSZ)
#define QT 128
#define NQT (TSZ / QT)   // 32
#define CPB 272          // chunks per batch = sum_qt ceil((qt+1)/2)
#define MAXC 16          // max chunks per (b,qt)

typedef _Float16 half8 __attribute__((ext_vector_type(8)));
typedef _Float16 half4 __attribute__((ext_vector_type(4)));
typedef float f32x4 __attribute__((ext_vector_type(4)));
typedef float f32x16 __attribute__((ext_vector_type(16)));

#define MFMA(a, b, c) __builtin_amdgcn_mfma_f32_16x16x32_f16((a), (b), (c), 0, 0, 0)
#define MFMA32(a, b, c) __builtin_amdgcn_mfma_f32_32x32x16_f16((a), (b), (c), 0, 0, 0)
#define QSCALE 0.04508422002778011f  // (1/32) * log2(e)

// tile-image index helpers (64x64 fp16 tiles, XOR-swizzled chunks of 8)
__device__ __forceinline__ int kimg(int r, int h) {  // r=key-in-tile, h=dim
    return r * 64 + (((h >> 3) ^ (r & 7)) << 3) + (h & 7);
}
__device__ __forceinline__ int vimg(int kk, int h) {  // kk=key-in-tile, h=dim
    return h * 64 + (((kk >> 3) ^ (h & 7)) << 3) + (kk & 7);
}

__device__ __forceinline__ void glds16(const _Float16* g, _Float16* l) {
    __builtin_amdgcn_global_load_lds(
        (const __attribute__((address_space(1))) void*)g,
        (__attribute__((address_space(3))) void*)l, 16, 0, 0);
}

// ---------------------------------------------------------------------------
// Kernel 1: weights fp32->fp16 into a SWIZZLED image for proj's DMA:
// Wt[n*1024 + g*64 + ((c ^ (n&7))*8 + j)] = W[(g*64+c*8+j)*64 + n%64]
// Also zeroes the 128 per-(b,qt) combine counters (block 0).
// ---------------------------------------------------------------------------
__global__ __launch_bounds__(192) void wconv(const float* __restrict__ Wk,
                                             const float* __restrict__ Wq,
                                             const float* __restrict__ Wv,
                                             _Float16* __restrict__ Wt,
                                             int* __restrict__ cnt) {
    int k = blockIdx.x;   // 0..1023
    int n = threadIdx.x;  // 0..191
    if (k == 0 && n < BSZ * NQT) cnt[n] = 0;
    int g = k >> 6, c = (k >> 3) & 7, j = k & 7;
    const float* W = (n < 64) ? Wk : ((n < 128) ? Wq : Wv);
    float v = W[k * 64 + (n & 63)];
    if (n >= 64 && n < 128) v *= QSCALE;
    Wt[(size_t)n * 1024 + g * 64 + ((c ^ (n & 7)) << 3) + j] = (_Float16)v;
}

// ---------------------------------------------------------------------------
// Kernel 2: QKV proj. Mtile=64 (grid 256, 512 thr, 8 waves), BK=64.
// W tile (24 KB) via DMA from swizzled image, x tile (8 KB) via reg-cvt
// swizzled stores; both dbuf; one barrier/step. Epilogue: Q row-major;
// K+V as interleaved 8KB tile records (V transposed).
// Block->row0 remap so batch b's outputs are produced on XCD {2b,2b+1}.
// ---------------------------------------------------------------------------
__global__ __launch_bounds__(512) void qkv_proj(
    const float* __restrict__ x, const _Float16* __restrict__ Wt,
    _Float16* __restrict__ qbf, _Float16* __restrict__ kvs) {
    __shared__ _Float16 wt[2][192 * 64];  // 24 KB each
    __shared__ _Float16 xt[2][64 * 64];   // 8 KB each

    int tid = threadIdx.x;
    int wave = tid >> 6, lane = tid & 63;
    int quad = lane >> 4, l16 = lane & 15;
    // XCD-pair-per-batch swizzle: xcd = id&7 owns batch xcd>>1.
    int id = blockIdx.x;
    int xcd = id & 7;
    int rb = (id >> 3) * 2 + (xcd & 1);       // 0..63: row-tile within batch
    int row0 = (xcd >> 1) * TSZ + rb * 64;
    int mh = wave >> 2;           // 0..1 : 32-row half
    int ctb = (wave & 3) * 3;     // ct trio base

    f32x4 acc[6];  // [j][strip]
#pragma unroll
    for (int i = 0; i < 6; i++) acc[i] = (f32x4){0.f, 0.f, 0.f, 0.f};

    int sr = tid >> 3, sc = tid & 7;  // 64 rows x 8 chunks of 8 floats
    const float* xrow = x + (size_t)(row0 + sr) * CSZ + sc * 8;
    f32x4 p0 = *(const f32x4*)xrow;
    f32x4 p1 = *(const f32x4*)(xrow + 4);

#pragma unroll
    for (int i = 0; i < 3; i++) {
        int g = i * 512 + tid;
        glds16(Wt + ((size_t)(g >> 3)) * 1024 + (g & 7) * 8,
               &wt[0][(size_t)g * 8]);
    }

    int cur = 0;
    for (int kc = 0; kc < CSZ; kc += 64, cur ^= 1) {
        {
            _Float16 tmp[8] __attribute__((aligned(16)));
#pragma unroll
            for (int i = 0; i < 4; i++) {
                tmp[i] = (_Float16)p0[i];
                tmp[4 + i] = (_Float16)p1[i];
            }
            *(half8*)&xt[cur][sr * 64 + ((sc ^ (sr & 7)) << 3)] = *(half8*)tmp;
        }
        __syncthreads();  // drains W-DMA for wt[cur]; xt[cur] visible

        if (kc + 64 < CSZ) {
#pragma unroll
            for (int i = 0; i < 3; i++) {
                int g = i * 512 + tid;
                glds16(Wt + ((size_t)(g >> 3)) * 1024 + (kc + 64) + (g & 7) * 8,
                       &wt[cur ^ 1][(size_t)g * 8]);
            }
            p0 = *(const f32x4*)(xrow + kc + 64);
            p1 = *(const f32x4*)(xrow + kc + 68);
        }

#pragma unroll
        for (int ss = 0; ss < 2; ss++) {
            half8 a0 = *(half8*)&xt[cur][(mh * 32 + l16) * 64 +
                                         (((ss * 4 + quad) ^ (l16 & 7)) << 3)];
            half8 a1 = *(half8*)&xt[cur][(mh * 32 + 16 + l16) * 64 +
                                         (((ss * 4 + quad) ^ (l16 & 7)) << 3)];
#pragma unroll
            for (int j = 0; j < 3; j++) {
                int ct = ctb + j;
                half8 bb = *(half8*)&wt[cur][(ct * 16 + l16) * 64 +
                                             (((ss * 4 + quad) ^ (l16 & 7))
                                              << 3)];
                acc[j * 2 + 0] = MFMA(a0, bb, acc[j * 2 + 0]);
                acc[j * 2 + 1] = MFMA(a1, bb, acc[j * 2 + 1]);
            }
        }
    }

#pragma unroll
    for (int j = 0; j < 3; j++) {
        int ct = ctb + j;
        int kind = ct >> 2;
        int col = (ct & 3) * 16 + l16;
#pragma unroll
        for (int m = 0; m < 2; m++) {
#pragma unroll
            for (int r = 0; r < 4; r++) {
                int row = row0 + mh * 32 + m * 16 + quad * 4 + r;
                _Float16 val = (_Float16)acc[j * 2 + m][r];
                if (kind == 0) {
                    kvs[((size_t)(row >> 6)) * 8192 + kimg(row & 63, col)] = val;
                } else if (kind == 1) {
                    qbf[(size_t)row * 64 + col] = val;
                } else {
                    kvs[((size_t)(row >> 6)) * 8192 + 4096 +
                        vimg(row & 63, col)] = val;
                }
            }
        }
    }
}

// ---------------------------------------------------------------------------
// Kernel 3: flat balanced split-K flash attention, no-max softmax.
// Swapped 32x32x16 MFMA: S^T = mfma(K, Q) -> C col (lane&31) = q row,
// C row = key = (reg&3)+8*(reg>>2)+4*(lane>>5). P stays in registers:
// cvt_pkrtz pairs + permlane32_swap build the PV A-fragments directly.
// 4 waves x 32 q rows. K/V: one 8KB interleaved record per key-tile,
// DMA to dbuf LDS, 1 barrier/tile. (core = R11 verbatim)
// R14 epilogue: last chunk of each (b,qt) runs the combine in-kernel.
// ---------------------------------------------------------------------------
__global__ __launch_bounds__(256, 4) void attn_partial(
    const _Float16* __restrict__ qbf, const _Float16* __restrict__ kvs,
    _Float16* __restrict__ opart, float* __restrict__ ml,
    float* __restrict__ out, int* __restrict__ cnt) {
    __shared__ _Float16 kt[2][4096];
    __shared__ _Float16 vt[2][4096];
    __shared__ float ls[4][32];
    __shared__ int lastf;

    int tid = threadIdx.x;
    int wave = tid >> 6, lane = tid & 63;
    int l32 = lane & 31, hi = lane >> 5;

    // block -> (b, qt, chunk): XCD-pair-per-batch swizzle
    int id = blockIdx.x;
    int xcd = id & 7;
    int b = xcd >> 1;
    int id2 = (id >> 3) * 2 + (xcd & 1);  // 0..271
    int qt = 0;
    while (qt < NQT - 1 && (((qt + 2) * (qt + 2)) >> 2) <= id2) qt++;
    int chunk = id2 - (((qt + 1) * (qt + 1)) >> 2);
    int nt = 2 * (qt + 1);
    int lo = chunk * 4;
    int hic = min(lo + 4, nt);
    int nc = (qt + 2) >> 1;
    int part = (b * NQT + qt) * MAXC + chunk;

    const _Float16* qb = qbf + (size_t)b * TSZ * 64;
    const _Float16* kvb = kvs + (size_t)b * 64 * 8192;

    int qrow = qt * QT + wave * 32 + l32;  // this lane's q row (batch-local)
    half8 aq[4];                            // Q[qrow][ss*16 + hi*8 .. +8)
#pragma unroll
    for (int ss = 0; ss < 4; ss++)
        aq[ss] = *(const half8*)&qb[(size_t)qrow * 64 + ss * 16 + hi * 8];

    f32x16 o[2];
#pragma unroll
    for (int i = 0; i < 16; i++) { o[0][i] = 0.f; o[1][i] = 0.f; }
    float l_acc = 0.f;

    int soff = wave * 512 + lane * 8;  // 0..2047 halves across block

    {
        const _Float16* p0 = kvb + (size_t)lo * 8192 + soff;
        glds16(p0, &kt[0][soff]);
        glds16(p0 + 2048, &kt[0][2048 + soff]);
        glds16(p0 + 4096, &vt[0][soff]);
        glds16(p0 + 6144, &vt[0][2048 + soff]);
    }

    int cur = 0;
    for (int kti = lo; kti < hic; kti++, cur ^= 1) {
        __syncthreads();  // drains DMA for [cur]; frees [cur^1]
        if (kti + 1 < hic) {
            const _Float16* p0 = kvb + (size_t)(kti + 1) * 8192 + soff;
            glds16(p0, &kt[cur ^ 1][soff]);
            glds16(p0 + 2048, &kt[cur ^ 1][2048 + soff]);
            glds16(p0 + 4096, &vt[cur ^ 1][soff]);
            glds16(p0 + 6144, &vt[cur ^ 1][2048 + soff]);
        }

        bool diag = (kti >= 2 * qt);
        int qrel = qrow - kti * 64;                      // per-lane
        int wmax = qt * QT + wave * 32 + 31 - kti * 64;  // wave-uniform

#pragma unroll
        for (int ctk = 0; ctk < 2; ctk++) {
            if (diag && ctk * 32 > wmax) continue;  // whole 32-key block masked

            f32x16 s;
#pragma unroll
            for (int i = 0; i < 16; i++) s[i] = 0.f;
            __builtin_amdgcn_s_setprio(1);
#pragma unroll
            for (int ss = 0; ss < 4; ss++) {
                half8 ak = *(half8*)&kt[cur][kimg(ctk * 32 + l32,
                                                  ss * 16 + hi * 8)];
                s = MFMA32(ak, aq[ss], s);
            }
            __builtin_amdgcn_s_setprio(0);

            // softmax: e = exp2(s), causal mask, row-partial into l_acc
            float e[16];
#pragma unroll
            for (int r = 0; r < 16; r++) {
                float ev = __builtin_amdgcn_exp2f(s[r]);
                if (diag) {
                    int key = ctk * 32 + (r & 3) + 8 * (r >> 2) + 4 * hi;
                    if (key > qrel) ev = 0.f;
                }
                e[r] = ev;
                l_acc += ev;
            }

            // pack pairs (key even, key+1) -> pk dwords
            unsigned pk[8];
#pragma unroll
            for (int p = 0; p < 8; p++) {
                auto h2 = __builtin_amdgcn_cvt_pkrtz(e[2 * p], e[2 * p + 1]);
                union { decltype(h2) h; unsigned u; } cv;
                cv.h = h2;
                pk[p] = cv.u;
            }
            // permlane32_swap(vdst, vsrc): vdst[32:63] <-> vsrc[0:31].
            // swap(p, p+2): p-slot -> A.dw[d] (lo-half source),
            //               (p+2)-slot -> A.dw[d+2] (hi-half source).
            asm("v_permlane32_swap_b32 %0, %1" : "+v"(pk[0]), "+v"(pk[2]));
            asm("v_permlane32_swap_b32 %0, %1" : "+v"(pk[1]), "+v"(pk[3]));
            asm("v_permlane32_swap_b32 %0, %1" : "+v"(pk[4]), "+v"(pk[6]));
            asm("v_permlane32_swap_b32 %0, %1" : "+v"(pk[5]), "+v"(pk[7]));
            union { unsigned u[4]; half8 h; } A0, A1;
            A0.u[0] = pk[0]; A0.u[1] = pk[1]; A0.u[2] = pk[2]; A0.u[3] = pk[3];
            A1.u[0] = pk[4]; A1.u[1] = pk[5]; A1.u[2] = pk[6]; A1.u[3] = pk[7];

            __builtin_amdgcn_s_setprio(1);
#pragma unroll
            for (int cth = 0; cth < 2; cth++) {
                int h = cth * 32 + l32;
                half8 v0 = *(half8*)&vt[cur][vimg((2 * ctk + 0) * 16 + hi * 8, h)];
                half8 v1 = *(half8*)&vt[cur][vimg((2 * ctk + 1) * 16 + hi * 8, h)];
                o[cth] = MFMA32(A0.h, v0, o[cth]);
                o[cth] = MFMA32(A1.h, v1, o[cth]);
            }
            __builtin_amdgcn_s_setprio(0);
        }
    }

    // row sum lives split across hi halves only
    l_acc += __shfl_xor(l_acc, 32);
    float inv = l_acc > 0.f ? 1.f / l_acc : 0.f;
    if (!hi) ls[wave][l32] = inv;  // q-local -> inv, per-wave private

    if (nc == 1) {
        // single-chunk group: write final output directly, skip opart/ml
        float* ob = out + ((size_t)(b * TSZ + qt * QT)) * 64;
#pragma unroll
        for (int r = 0; r < 16; r++) {
            int rl = (r & 3) + 8 * (r >> 2) + 4 * hi;
            float invr = ls[wave][rl];
            int lrow = wave * 32 + rl;
            ob[lrow * 64 + l32] = o[0][r] * invr;
            ob[lrow * 64 + 32 + l32] = o[1][r] * invr;
        }
        return;
    }

    _Float16* op = opart + (size_t)part * (QT * 64);
#pragma unroll
    for (int r = 0; r < 16; r++) {
        int rl = (r & 3) + 8 * (r >> 2) + 4 * hi;  // q row of this acc reg
        float invr = ls[wave][rl];
        int lrow = wave * 32 + rl;
        op[lrow * 64 + l32] = (_Float16)(o[0][r] * invr);
        op[lrow * 64 + 32 + l32] = (_Float16)(o[1][r] * invr);
    }
    if (!hi) ml[part * QT + wave * 32 + l32] = l_acc;

    // ---- fused combine: arriving-last chunk reduces this (b,qt) ----
    __syncthreads();  // all partial stores issued + vmcnt-drained
    if (tid == 0) {
        __threadfence();  // release: flush this XCD's L2 to device scope
        int old = __hip_atomic_fetch_add(cnt + (b * NQT + qt), 1,
                                         __ATOMIC_ACQ_REL,
                                         __HIP_MEMORY_SCOPE_AGENT);
        lastf = (old == nc - 1);
    }
    __syncthreads();
    if (!lastf) return;
    __threadfence();  // acquire: invalidate stale lines before reading peers

    const _Float16* opq = opart + (size_t)(b * NQT + qt) * MAXC * (QT * 64);
    const float* mlq = ml + (size_t)(b * NQT + qt) * MAXC * QT;
    float* ob = out + ((size_t)(b * TSZ + qt * QT)) * 64;
#pragma unroll
    for (int pass = 0; pass < 4; pass++) {
        int prow = pass * 32 + (tid >> 3);
        int seg = (tid & 7) * 8;
        float acc[8];
#pragma unroll
        for (int i = 0; i < 8; i++) acc[i] = 0.f;
        float lsum = 0.f;
        for (int s2 = 0; s2 < nc; s2++) {
            float l = mlq[s2 * QT + prow];
            lsum += l;
            half8 h = *(const half8*)&opq[(size_t)s2 * (QT * 64) +
                                          prow * 64 + seg];
#pragma unroll
            for (int i = 0; i < 8; i++) acc[i] += l * (float)h[i];
        }
        float invf = 1.f / lsum;
#pragma unroll
        for (int i = 0; i < 8; i++) ob[prow * 64 + seg + i] = acc[i] * invf;
    }
}

// ---------------------------------------------------------------------------
extern "C" void kernel_launch(void* const* d_in, const int* in_sizes, int n_in,
                              void* d_out, int out_size, void* d_ws,
                              size_t ws_size, hipStream_t stream) {
    (void)in_sizes; (void)n_in; (void)out_size; (void)ws_size;
    const float* x = (const float*)d_in[0];
    const float* Wk = (const float*)d_in[1];
    const float* Wq = (const float*)d_in[2];
    const float* Wv = (const float*)d_in[3];

    _Float16* Wt = (_Float16*)d_ws;                       // 192*1024
    _Float16* qbf = Wt + 192 * 1024;                      // MSZ*64
    _Float16* kvs = qbf + (size_t)MSZ * 64;               // 256 tiles * 8192
    _Float16* opart = kvs + (size_t)MSZ * 128;            // 2048 * 8192
    float* ml = (float*)(opart + (size_t)BSZ * NQT * MAXC * QT * 64);
    int* cnt = (int*)(ml + (size_t)BSZ * NQT * MAXC * QT);  // 128 ints

    wconv<<<1024, 192, 0, stream>>>(Wk, Wq, Wv, Wt, cnt);
    qkv_proj<<<MSZ / 64, 512, 0, stream>>>(x, Wt, qbf, kvs);
    attn_partial<<<BSZ * CPB, 256, 0, stream>>>(qbf, kvs, opart, ml,
                                                (float*)d_out, cnt);
}

// Round 5
// 147.171 us; speedup vs baseline: 1.5920x; 1.5920x over previous
//
#include <hip/hip_runtime.h>

// Single-head causal attention. B=4, T=4096, C=1024, H=64, fp32 io.
// scale = C**-0.5 = 1/32, folded with log2(e) into Wq (no-max softmax:
// scores*scale ~ N(0,0.25^2) -> exp2 of raw scores safe, fp16 P safe).
// R15: fusion REVERTED (R14's per-block device-scope fences forced L2
//      writeback/invalidate ~1020x -> all K/V DMA served at L3 latency,
//      attn 40->126us). Back to R13's 4-kernel structure, plus:
//  - attn: __builtin_amdgcn_exp2f (passed in R14), s_setprio REMOVED
//    (m190: setprio ~0/negative for barrier-locked multi-wave blocks),
//    nc==1 (qt<=1) blocks write fp32 out directly (passed in R14).
//  - combine: early-exit for nc==1 rows (attn wrote them).
//  - qkv_proj: Mtile 64->32 (256 thr, grid 512, LDS 56KB -> 2 blocks/CU):
//    overlaps the per-iter x HBM prefetch latency across 2 blocks
//    (was 1 block/CU -> ~500cy exposed stall per K-step).

#define BSZ 4
#define TSZ 4096
#define CSZ 1024
#define MSZ (BSZ * TSZ)
#define QT 128
#define NQT (TSZ / QT)   // 32
#define CPB 272          // chunks per batch = sum_qt ceil((qt+1)/2)
#define MAXC 16          // max chunks per (b,qt)

typedef _Float16 half8 __attribute__((ext_vector_type(8)));
typedef _Float16 half4 __attribute__((ext_vector_type(4)));
typedef float f32x4 __attribute__((ext_vector_type(4)));
typedef float f32x16 __attribute__((ext_vector_type(16)));

#define MFMA(a, b, c) __builtin_amdgcn_mfma_f32_16x16x32_f16((a), (b), (c), 0, 0, 0)
#define MFMA32(a, b, c) __builtin_amdgcn_mfma_f32_32x32x16_f16((a), (b), (c), 0, 0, 0)
#define QSCALE 0.04508422002778011f  // (1/32) * log2(e)

// tile-image index helpers (64x64 fp16 tiles, XOR-swizzled chunks of 8)
__device__ __forceinline__ int kimg(int r, int h) {  // r=key-in-tile, h=dim
    return r * 64 + (((h >> 3) ^ (r & 7)) << 3) + (h & 7);
}
__device__ __forceinline__ int vimg(int kk, int h) {  // kk=key-in-tile, h=dim
    return h * 64 + (((kk >> 3) ^ (h & 7)) << 3) + (kk & 7);
}

__device__ __forceinline__ void glds16(const _Float16* g, _Float16* l) {
    __builtin_amdgcn_global_load_lds(
        (const __attribute__((address_space(1))) void*)g,
        (__attribute__((address_space(3))) void*)l, 16, 0, 0);
}

// ---------------------------------------------------------------------------
// Kernel 1: weights fp32->fp16 into a SWIZZLED image for proj's DMA:
// Wt[n*1024 + g*64 + ((c ^ (n&7))*8 + j)] = W[(g*64+c*8+j)*64 + n%64]
// ---------------------------------------------------------------------------
__global__ __launch_bounds__(192) void wconv(const float* __restrict__ Wk,
                                             const float* __restrict__ Wq,
                                             const float* __restrict__ Wv,
                                             _Float16* __restrict__ Wt) {
    int k = blockIdx.x;   // 0..1023
    int n = threadIdx.x;  // 0..191
    int g = k >> 6, c = (k >> 3) & 7, j = k & 7;
    const float* W = (n < 64) ? Wk : ((n < 128) ? Wq : Wv);
    float v = W[k * 64 + (n & 63)];
    if (n >= 64 && n < 128) v *= QSCALE;
    Wt[(size_t)n * 1024 + g * 64 + ((c ^ (n & 7)) << 3) + j] = (_Float16)v;
}

// ---------------------------------------------------------------------------
// Kernel 2: QKV proj. R15: Mtile=32 (grid 512, 256 thr, 4 waves), BK=64.
// W tile (24 KB) via DMA from swizzled image, x tile (4 KB) via reg-cvt
// swizzled stores; both dbuf; one barrier/step. LDS 56 KB -> 2 blocks/CU.
// Epilogue: Q row-major; K+V as interleaved tile records (V transposed).
// Block->row0 remap so batch b's outputs are produced on XCD {2b,2b+1}.
// ---------------------------------------------------------------------------
__global__ __launch_bounds__(256) void qkv_proj(
    const float* __restrict__ x, const _Float16* __restrict__ Wt,
    _Float16* __restrict__ qbf, _Float16* __restrict__ kvs) {
    __shared__ _Float16 wt[2][192 * 64];  // 24 KB each
    __shared__ _Float16 xt[2][32 * 64];   // 4 KB each

    int tid = threadIdx.x;
    int wave = tid >> 6, lane = tid & 63;
    int quad = lane >> 4, l16 = lane & 15;
    // XCD-pair-per-batch swizzle: xcd = id&7 owns batch xcd>>1.
    int id = blockIdx.x;
    int xcd = id & 7;
    int rb = (id >> 3) * 2 + (xcd & 1);       // 0..127: row-tile within batch
    int row0 = (xcd >> 1) * TSZ + rb * 32;
    int ctb = wave * 3;  // ct trio base, ct in 0..11

    f32x4 acc[6];  // [j][strip]
#pragma unroll
    for (int i = 0; i < 6; i++) acc[i] = (f32x4){0.f, 0.f, 0.f, 0.f};

    int sr = tid >> 3, sc = tid & 7;  // 32 rows x 8 chunks of 8 floats
    const float* xrow = x + (size_t)(row0 + sr) * CSZ + sc * 8;
    f32x4 p0 = *(const f32x4*)xrow;
    f32x4 p1 = *(const f32x4*)(xrow + 4);

#pragma unroll
    for (int i = 0; i < 6; i++) {
        int g = i * 256 + tid;
        glds16(Wt + ((size_t)(g >> 3)) * 1024 + (g & 7) * 8,
               &wt[0][(size_t)g * 8]);
    }

    int cur = 0;
    for (int kc = 0; kc < CSZ; kc += 64, cur ^= 1) {
        {
            _Float16 tmp[8] __attribute__((aligned(16)));
#pragma unroll
            for (int i = 0; i < 4; i++) {
                tmp[i] = (_Float16)p0[i];
                tmp[4 + i] = (_Float16)p1[i];
            }
            *(half8*)&xt[cur][sr * 64 + ((sc ^ (sr & 7)) << 3)] = *(half8*)tmp;
        }
        __syncthreads();  // drains W-DMA for wt[cur]; xt[cur] visible

        if (kc + 64 < CSZ) {
#pragma unroll
            for (int i = 0; i < 6; i++) {
                int g = i * 256 + tid;
                glds16(Wt + ((size_t)(g >> 3)) * 1024 + (kc + 64) + (g & 7) * 8,
                       &wt[cur ^ 1][(size_t)g * 8]);
            }
            p0 = *(const f32x4*)(xrow + kc + 64);
            p1 = *(const f32x4*)(xrow + kc + 68);
        }

#pragma unroll
        for (int ss = 0; ss < 2; ss++) {
            half8 a0 = *(half8*)&xt[cur][l16 * 64 +
                                         (((ss * 4 + quad) ^ (l16 & 7)) << 3)];
            half8 a1 = *(half8*)&xt[cur][(16 + l16) * 64 +
                                         (((ss * 4 + quad) ^ (l16 & 7)) << 3)];
#pragma unroll
            for (int j = 0; j < 3; j++) {
                int ct = ctb + j;
                half8 bb = *(half8*)&wt[cur][(ct * 16 + l16) * 64 +
                                             (((ss * 4 + quad) ^ (l16 & 7))
                                              << 3)];
                acc[j * 2 + 0] = MFMA(a0, bb, acc[j * 2 + 0]);
                acc[j * 2 + 1] = MFMA(a1, bb, acc[j * 2 + 1]);
            }
        }
    }

#pragma unroll
    for (int j = 0; j < 3; j++) {
        int ct = ctb + j;
        int kind = ct >> 2;
        int col = (ct & 3) * 16 + l16;
#pragma unroll
        for (int m = 0; m < 2; m++) {
#pragma unroll
            for (int r = 0; r < 4; r++) {
                int row = row0 + m * 16 + quad * 4 + r;
                _Float16 val = (_Float16)acc[j * 2 + m][r];
                if (kind == 0) {
                    kvs[((size_t)(row >> 6)) * 8192 + kimg(row & 63, col)] = val;
                } else if (kind == 1) {
                    qbf[(size_t)row * 64 + col] = val;
                } else {
                    kvs[((size_t)(row >> 6)) * 8192 + 4096 +
                        vimg(row & 63, col)] = val;
                }
            }
        }
    }
}

// ---------------------------------------------------------------------------
// Kernel 3: flat balanced split-K flash attention, no-max softmax.
// Swapped 32x32x16 MFMA: S^T = mfma(K, Q) -> C col (lane&31) = q row,
// C row = key = (reg&3)+8*(reg>>2)+4*(lane>>5). P stays in registers:
// cvt_pkrtz pairs + permlane32_swap build the PV A-fragments directly.
// 4 waves x 32 q rows. K/V: one interleaved record per key-tile,
// DMA to dbuf LDS, 1 barrier/tile. (core = R11/R13; setprio removed,
// exp2 builtin, nc==1 writes fp32 out directly.)
// ---------------------------------------------------------------------------
__global__ __launch_bounds__(256, 4) void attn_partial(
    const _Float16* __restrict__ qbf, const _Float16* __restrict__ kvs,
    _Float16* __restrict__ opart, float* __restrict__ ml,
    float* __restrict__ out) {
    __shared__ _Float16 kt[2][4096];
    __shared__ _Float16 vt[2][4096];
    __shared__ float ls[4][32];

    int tid = threadIdx.x;
    int wave = tid >> 6, lane = tid & 63;
    int l32 = lane & 31, hi = lane >> 5;

    // block -> (b, qt, chunk): XCD-pair-per-batch swizzle
    int id = blockIdx.x;
    int xcd = id & 7;
    int b = xcd >> 1;
    int id2 = (id >> 3) * 2 + (xcd & 1);  // 0..271
    int qt = 0;
    while (qt < NQT - 1 && (((qt + 2) * (qt + 2)) >> 2) <= id2) qt++;
    int chunk = id2 - (((qt + 1) * (qt + 1)) >> 2);
    int nt = 2 * (qt + 1);
    int lo = chunk * 4;
    int hic = min(lo + 4, nt);
    int nc = (qt + 2) >> 1;
    int part = (b * NQT + qt) * MAXC + chunk;

    const _Float16* qb = qbf + (size_t)b * TSZ * 64;
    const _Float16* kvb = kvs + (size_t)b * 64 * 8192;

    int qrow = qt * QT + wave * 32 + l32;  // this lane's q row (batch-local)
    half8 aq[4];                            // Q[qrow][ss*16 + hi*8 .. +8)
#pragma unroll
    for (int ss = 0; ss < 4; ss++)
        aq[ss] = *(const half8*)&qb[(size_t)qrow * 64 + ss * 16 + hi * 8];

    f32x16 o[2];
#pragma unroll
    for (int i = 0; i < 16; i++) { o[0][i] = 0.f; o[1][i] = 0.f; }
    float l_acc = 0.f;

    int soff = wave * 512 + lane * 8;  // 0..2047 halves across block

    {
        const _Float16* p0 = kvb + (size_t)lo * 8192 + soff;
        glds16(p0, &kt[0][soff]);
        glds16(p0 + 2048, &kt[0][2048 + soff]);
        glds16(p0 + 4096, &vt[0][soff]);
        glds16(p0 + 6144, &vt[0][2048 + soff]);
    }

    int cur = 0;
    for (int kti = lo; kti < hic; kti++, cur ^= 1) {
        __syncthreads();  // drains DMA for [cur]; frees [cur^1]
        if (kti + 1 < hic) {
            const _Float16* p0 = kvb + (size_t)(kti + 1) * 8192 + soff;
            glds16(p0, &kt[cur ^ 1][soff]);
            glds16(p0 + 2048, &kt[cur ^ 1][2048 + soff]);
            glds16(p0 + 4096, &vt[cur ^ 1][soff]);
            glds16(p0 + 6144, &vt[cur ^ 1][2048 + soff]);
        }

        bool diag = (kti >= 2 * qt);
        int qrel = qrow - kti * 64;                      // per-lane
        int wmax = qt * QT + wave * 32 + 31 - kti * 64;  // wave-uniform

#pragma unroll
        for (int ctk = 0; ctk < 2; ctk++) {
            if (diag && ctk * 32 > wmax) continue;  // whole 32-key block masked

            f32x16 s;
#pragma unroll
            for (int i = 0; i < 16; i++) s[i] = 0.f;
#pragma unroll
            for (int ss = 0; ss < 4; ss++) {
                half8 ak = *(half8*)&kt[cur][kimg(ctk * 32 + l32,
                                                  ss * 16 + hi * 8)];
                s = MFMA32(ak, aq[ss], s);
            }

            // softmax: e = exp2(s), causal mask, row-partial into l_acc
            float e[16];
#pragma unroll
            for (int r = 0; r < 16; r++) {
                float ev = __builtin_amdgcn_exp2f(s[r]);
                if (diag) {
                    int key = ctk * 32 + (r & 3) + 8 * (r >> 2) + 4 * hi;
                    if (key > qrel) ev = 0.f;
                }
                e[r] = ev;
                l_acc += ev;
            }

            // pack pairs (key even, key+1) -> pk dwords
            unsigned pk[8];
#pragma unroll
            for (int p = 0; p < 8; p++) {
                auto h2 = __builtin_amdgcn_cvt_pkrtz(e[2 * p], e[2 * p + 1]);
                union { decltype(h2) h; unsigned u; } cv;
                cv.h = h2;
                pk[p] = cv.u;
            }
            // permlane32_swap(vdst, vsrc): vdst[32:63] <-> vsrc[0:31].
            // swap(p, p+2): p-slot -> A.dw[d] (lo-half source),
            //               (p+2)-slot -> A.dw[d+2] (hi-half source).
            asm("v_permlane32_swap_b32 %0, %1" : "+v"(pk[0]), "+v"(pk[2]));
            asm("v_permlane32_swap_b32 %0, %1" : "+v"(pk[1]), "+v"(pk[3]));
            asm("v_permlane32_swap_b32 %0, %1" : "+v"(pk[4]), "+v"(pk[6]));
            asm("v_permlane32_swap_b32 %0, %1" : "+v"(pk[5]), "+v"(pk[7]));
            union { unsigned u[4]; half8 h; } A0, A1;
            A0.u[0] = pk[0]; A0.u[1] = pk[1]; A0.u[2] = pk[2]; A0.u[3] = pk[3];
            A1.u[0] = pk[4]; A1.u[1] = pk[5]; A1.u[2] = pk[6]; A1.u[3] = pk[7];

#pragma unroll
            for (int cth = 0; cth < 2; cth++) {
                int h = cth * 32 + l32;
                half8 v0 = *(half8*)&vt[cur][vimg((2 * ctk + 0) * 16 + hi * 8, h)];
                half8 v1 = *(half8*)&vt[cur][vimg((2 * ctk + 1) * 16 + hi * 8, h)];
                o[cth] = MFMA32(A0.h, v0, o[cth]);
                o[cth] = MFMA32(A1.h, v1, o[cth]);
            }
        }
    }

    // row sum lives split across hi halves only
    l_acc += __shfl_xor(l_acc, 32);
    float inv = l_acc > 0.f ? 1.f / l_acc : 0.f;
    if (!hi) ls[wave][l32] = inv;  // q-local -> inv, per-wave private

    if (nc == 1) {
        // single-chunk group (qt<=1): write final fp32 output directly
        float* ob = out + ((size_t)(b * TSZ + qt * QT)) * 64;
#pragma unroll
        for (int r = 0; r < 16; r++) {
            int rl = (r & 3) + 8 * (r >> 2) + 4 * hi;
            float invr = ls[wave][rl];
            int lrow = wave * 32 + rl;
            ob[lrow * 64 + l32] = o[0][r] * invr;
            ob[lrow * 64 + 32 + l32] = o[1][r] * invr;
        }
        return;
    }

    _Float16* op = opart + (size_t)part * (QT * 64);
#pragma unroll
    for (int r = 0; r < 16; r++) {
        int rl = (r & 3) + 8 * (r >> 2) + 4 * hi;  // q row of this acc reg
        float invr = ls[wave][rl];
        int lrow = wave * 32 + rl;
        op[lrow * 64 + l32] = (_Float16)(o[0][r] * invr);
        op[lrow * 64 + 32 + l32] = (_Float16)(o[1][r] * invr);
    }
    if (!hi) ml[part * QT + wave * 32 + l32] = l_acc;
}

// ---------------------------------------------------------------------------
// Kernel 4: combine nc(qt)=ceil((qt+1)/2) partials per row.
// Grid 512: 32 rows/block, 8 threads/row. XCD-pair swizzle matches attn's
// writer mapping so opart/ml reads are L2-local. nc==1 rows were written
// directly by attn -> early exit.
// ---------------------------------------------------------------------------
__global__ __launch_bounds__(256) void combine(
    const _Float16* __restrict__ opart, const float* __restrict__ ml,
    float* __restrict__ out) {
    int tid = threadIdx.x;
    int id = blockIdx.x;
    int xcd = id & 7;
    int b = xcd >> 1;
    int rb = (id >> 3) * 2 + (xcd & 1);  // 0..127: row-block within batch
    int row = b * TSZ + rb * 32 + (tid >> 3);
    int seg = (tid & 7) * 8;
    int qt = (row >> 7) & (NQT - 1);
    int nc = (qt + 2) >> 1;
    if (nc == 1) return;  // attn wrote these rows directly
    int prow = row & (QT - 1);
    int pbase = (b * NQT + qt) * MAXC;

    float acc[8];
#pragma unroll
    for (int i = 0; i < 8; i++) acc[i] = 0.f;
    float lsum = 0.f;
    for (int s = 0; s < nc; s++) {
        float l = ml[(pbase + s) * QT + prow];
        lsum += l;
        half8 h = *(const half8*)&opart[(size_t)(pbase + s) * (QT * 64) +
                                        prow * 64 + seg];
#pragma unroll
        for (int i = 0; i < 8; i++) acc[i] += l * (float)h[i];
    }
    float inv = 1.f / lsum;
    float* ob = out + (size_t)row * 64 + seg;
#pragma unroll
    for (int i = 0; i < 8; i++) ob[i] = acc[i] * inv;
}

// ---------------------------------------------------------------------------
extern "C" void kernel_launch(void* const* d_in, const int* in_sizes, int n_in,
                              void* d_out, int out_size, void* d_ws,
                              size_t ws_size, hipStream_t stream) {
    (void)in_sizes; (void)n_in; (void)out_size; (void)ws_size;
    const float* x = (const float*)d_in[0];
    const float* Wk = (const float*)d_in[1];
    const float* Wq = (const float*)d_in[2];
    const float* Wv = (const float*)d_in[3];

    _Float16* Wt = (_Float16*)d_ws;                       // 192*1024
    _Float16* qbf = Wt + 192 * 1024;                      // MSZ*64
    _Float16* kvs = qbf + (size_t)MSZ * 64;               // 256 tiles * 8192
    _Float16* opart = kvs + (size_t)MSZ * 128;            // 2048 * 8192
    float* ml = (float*)(opart + (size_t)BSZ * NQT * MAXC * QT * 64);

    wconv<<<1024, 192, 0, stream>>>(Wk, Wq, Wv, Wt);
    qkv_proj<<<MSZ / 32, 256, 0, stream>>>(x, Wt, qbf, kvs);
    attn_partial<<<BSZ * CPB, 256, 0, stream>>>(qbf, kvs, opart, ml,
                                                (float*)d_out);
    combine<<<MSZ / 32, 256, 0, stream>>>(opart, ml, (float*)d_out);
}

// Round 6
// 138.950 us; speedup vs baseline: 1.6861x; 1.0592x over previous
//
#include <hip/hip_runtime.h>

// Single-head causal attention. B=4, T=4096, C=1024, H=64, fp32 io.
// scale = C**-0.5 = 1/32, folded with log2(e) into Wq (no-max softmax:
// scores*scale ~ N(0,0.25^2) -> exp2 of raw scores safe, fp16 P safe).
// R16: attn CHUNK 4->5 key-tiles/block: chunks/batch 272->224, grid
//      1088->896 <= capacity 1024 (4 blocks/CU @ 33.8KB LDS) -> the whole
//      dispatch is ONE co-resident round (was 1024 + ragged 64-block tail
//      round ~ 2x block latency). Inner K-loop untouched.
//      qkv_proj reverted to R13's measured Mtile=64 version (R15's
//      Mtile=32 was the ~3us regressor: 2x W-DMA, worse amortization).
//      Kept: exp2 builtin, nc==1 direct fp32 out (absmax 0.0078),
//      setprio restored (R11/R13 config measured fastest; m191).

#define BSZ 4
#define TSZ 4096
#define CSZ 1024
#define MSZ (BSZ * TSZ)
#define QT 128
#define NQT (TSZ / QT)   // 32
#define CPB 224          // chunks per batch = sum_qt ceil(2(qt+1)/5)
#define MAXC 16          // max chunks per (b,qt) (need 13)

typedef _Float16 half8 __attribute__((ext_vector_type(8)));
typedef _Float16 half4 __attribute__((ext_vector_type(4)));
typedef float f32x4 __attribute__((ext_vector_type(4)));
typedef float f32x16 __attribute__((ext_vector_type(16)));

#define MFMA(a, b, c) __builtin_amdgcn_mfma_f32_16x16x32_f16((a), (b), (c), 0, 0, 0)
#define MFMA32(a, b, c) __builtin_amdgcn_mfma_f32_32x32x16_f16((a), (b), (c), 0, 0, 0)
#define QSCALE 0.04508422002778011f  // (1/32) * log2(e)

// tile-image index helpers (64x64 fp16 tiles, XOR-swizzled chunks of 8)
__device__ __forceinline__ int kimg(int r, int h) {  // r=key-in-tile, h=dim
    return r * 64 + (((h >> 3) ^ (r & 7)) << 3) + (h & 7);
}
__device__ __forceinline__ int vimg(int kk, int h) {  // kk=key-in-tile, h=dim
    return h * 64 + (((kk >> 3) ^ (h & 7)) << 3) + (kk & 7);
}

__device__ __forceinline__ void glds16(const _Float16* g, _Float16* l) {
    __builtin_amdgcn_global_load_lds(
        (const __attribute__((address_space(1))) void*)g,
        (__attribute__((address_space(3))) void*)l, 16, 0, 0);
}

// ---------------------------------------------------------------------------
// Kernel 1: weights fp32->fp16 into a SWIZZLED image for proj's DMA:
// Wt[n*1024 + g*64 + ((c ^ (n&7))*8 + j)] = W[(g*64+c*8+j)*64 + n%64]
// ---------------------------------------------------------------------------
__global__ __launch_bounds__(192) void wconv(const float* __restrict__ Wk,
                                             const float* __restrict__ Wq,
                                             const float* __restrict__ Wv,
                                             _Float16* __restrict__ Wt) {
    int k = blockIdx.x;   // 0..1023
    int n = threadIdx.x;  // 0..191
    int g = k >> 6, c = (k >> 3) & 7, j = k & 7;
    const float* W = (n < 64) ? Wk : ((n < 128) ? Wq : Wv);
    float v = W[k * 64 + (n & 63)];
    if (n >= 64 && n < 128) v *= QSCALE;
    Wt[(size_t)n * 1024 + g * 64 + ((c ^ (n & 7)) << 3) + j] = (_Float16)v;
}

// ---------------------------------------------------------------------------
// Kernel 2: QKV proj (R13 version). Mtile=64 (grid 256, 512 thr, 8 waves),
// BK=64. W tile (24 KB) via DMA from swizzled image, x tile (8 KB) via
// reg-cvt swizzled stores; both dbuf; one barrier/step. Epilogue: Q
// row-major; K+V as interleaved 8KB tile records (V transposed).
// Block->row0 remap so batch b's outputs are produced on XCD {2b,2b+1}.
// ---------------------------------------------------------------------------
__global__ __launch_bounds__(512) void qkv_proj(
    const float* __restrict__ x, const _Float16* __restrict__ Wt,
    _Float16* __restrict__ qbf, _Float16* __restrict__ kvs) {
    __shared__ _Float16 wt[2][192 * 64];  // 24 KB each
    __shared__ _Float16 xt[2][64 * 64];   // 8 KB each

    int tid = threadIdx.x;
    int wave = tid >> 6, lane = tid & 63;
    int quad = lane >> 4, l16 = lane & 15;
    // XCD-pair-per-batch swizzle: xcd = id&7 owns batch xcd>>1.
    int id = blockIdx.x;
    int xcd = id & 7;
    int rb = (id >> 3) * 2 + (xcd & 1);       // 0..63: row-tile within batch
    int row0 = (xcd >> 1) * TSZ + rb * 64;
    int mh = wave >> 2;           // 0..1 : 32-row half
    int ctb = (wave & 3) * 3;     // ct trio base

    f32x4 acc[6];  // [j][strip]
#pragma unroll
    for (int i = 0; i < 6; i++) acc[i] = (f32x4){0.f, 0.f, 0.f, 0.f};

    int sr = tid >> 3, sc = tid & 7;  // 64 rows x 8 chunks of 8 floats
    const float* xrow = x + (size_t)(row0 + sr) * CSZ + sc * 8;
    f32x4 p0 = *(const f32x4*)xrow;
    f32x4 p1 = *(const f32x4*)(xrow + 4);

#pragma unroll
    for (int i = 0; i < 3; i++) {
        int g = i * 512 + tid;
        glds16(Wt + ((size_t)(g >> 3)) * 1024 + (g & 7) * 8,
               &wt[0][(size_t)g * 8]);
    }

    int cur = 0;
    for (int kc = 0; kc < CSZ; kc += 64, cur ^= 1) {
        {
            _Float16 tmp[8] __attribute__((aligned(16)));
#pragma unroll
            for (int i = 0; i < 4; i++) {
                tmp[i] = (_Float16)p0[i];
                tmp[4 + i] = (_Float16)p1[i];
            }
            *(half8*)&xt[cur][sr * 64 + ((sc ^ (sr & 7)) << 3)] = *(half8*)tmp;
        }
        __syncthreads();  // drains W-DMA for wt[cur]; xt[cur] visible

        if (kc + 64 < CSZ) {
#pragma unroll
            for (int i = 0; i < 3; i++) {
                int g = i * 512 + tid;
                glds16(Wt + ((size_t)(g >> 3)) * 1024 + (kc + 64) + (g & 7) * 8,
                       &wt[cur ^ 1][(size_t)g * 8]);
            }
            p0 = *(const f32x4*)(xrow + kc + 64);
            p1 = *(const f32x4*)(xrow + kc + 68);
        }

#pragma unroll
        for (int ss = 0; ss < 2; ss++) {
            half8 a0 = *(half8*)&xt[cur][(mh * 32 + l16) * 64 +
                                         (((ss * 4 + quad) ^ (l16 & 7)) << 3)];
            half8 a1 = *(half8*)&xt[cur][(mh * 32 + 16 + l16) * 64 +
                                         (((ss * 4 + quad) ^ (l16 & 7)) << 3)];
#pragma unroll
            for (int j = 0; j < 3; j++) {
                int ct = ctb + j;
                half8 bb = *(half8*)&wt[cur][(ct * 16 + l16) * 64 +
                                             (((ss * 4 + quad) ^ (l16 & 7))
                                              << 3)];
                acc[j * 2 + 0] = MFMA(a0, bb, acc[j * 2 + 0]);
                acc[j * 2 + 1] = MFMA(a1, bb, acc[j * 2 + 1]);
            }
        }
    }

#pragma unroll
    for (int j = 0; j < 3; j++) {
        int ct = ctb + j;
        int kind = ct >> 2;
        int col = (ct & 3) * 16 + l16;
#pragma unroll
        for (int m = 0; m < 2; m++) {
#pragma unroll
            for (int r = 0; r < 4; r++) {
                int row = row0 + mh * 32 + m * 16 + quad * 4 + r;
                _Float16 val = (_Float16)acc[j * 2 + m][r];
                if (kind == 0) {
                    kvs[((size_t)(row >> 6)) * 8192 + kimg(row & 63, col)] = val;
                } else if (kind == 1) {
                    qbf[(size_t)row * 64 + col] = val;
                } else {
                    kvs[((size_t)(row >> 6)) * 8192 + 4096 +
                        vimg(row & 63, col)] = val;
                }
            }
        }
    }
}

// ---------------------------------------------------------------------------
// Kernel 3: flat balanced split-K flash attention, no-max softmax.
// Swapped 32x32x16 MFMA: S^T = mfma(K, Q) -> C col (lane&31) = q row,
// C row = key = (reg&3)+8*(reg>>2)+4*(lane>>5). P stays in registers:
// cvt_pkrtz pairs + permlane32_swap build the PV A-fragments directly.
// 4 waves x 32 q rows. K/V: one 8KB interleaved record per key-tile,
// DMA to dbuf LDS, 1 barrier/tile.
// R16: 5 key-tiles per chunk -> grid 896, one co-resident round.
// ---------------------------------------------------------------------------
__global__ __launch_bounds__(256, 4) void attn_partial(
    const _Float16* __restrict__ qbf, const _Float16* __restrict__ kvs,
    _Float16* __restrict__ opart, float* __restrict__ ml,
    float* __restrict__ out) {
    __shared__ _Float16 kt[2][4096];
    __shared__ _Float16 vt[2][4096];
    __shared__ float ls[4][32];

    int tid = threadIdx.x;
    int wave = tid >> 6, lane = tid & 63;
    int l32 = lane & 31, hi = lane >> 5;

    // block -> (b, qt, chunk): XCD-pair-per-batch swizzle
    int id = blockIdx.x;
    int xcd = id & 7;
    int b = xcd >> 1;
    int id2 = (id >> 3) * 2 + (xcd & 1);  // 0..223
    // scan: chunks(qt) = ceil(2(qt+1)/5) = (2qt+6)/5
    int qt = 0, base = 0;
    for (;;) {
        int c = (2 * qt + 6) / 5;
        if (id2 < base + c) break;
        base += c;
        qt++;
    }
    int chunk = id2 - base;
    int nt = 2 * (qt + 1);
    int lo = chunk * 5;
    int hic = min(lo + 5, nt);
    int nc = (2 * qt + 6) / 5;
    int part = (b * NQT + qt) * MAXC + chunk;

    const _Float16* qb = qbf + (size_t)b * TSZ * 64;
    const _Float16* kvb = kvs + (size_t)b * 64 * 8192;

    int qrow = qt * QT + wave * 32 + l32;  // this lane's q row (batch-local)
    half8 aq[4];                            // Q[qrow][ss*16 + hi*8 .. +8)
#pragma unroll
    for (int ss = 0; ss < 4; ss++)
        aq[ss] = *(const half8*)&qb[(size_t)qrow * 64 + ss * 16 + hi * 8];

    f32x16 o[2];
#pragma unroll
    for (int i = 0; i < 16; i++) { o[0][i] = 0.f; o[1][i] = 0.f; }
    float l_acc = 0.f;

    int soff = wave * 512 + lane * 8;  // 0..2047 halves across block

    {
        const _Float16* p0 = kvb + (size_t)lo * 8192 + soff;
        glds16(p0, &kt[0][soff]);
        glds16(p0 + 2048, &kt[0][2048 + soff]);
        glds16(p0 + 4096, &vt[0][soff]);
        glds16(p0 + 6144, &vt[0][2048 + soff]);
    }

    int cur = 0;
    for (int kti = lo; kti < hic; kti++, cur ^= 1) {
        __syncthreads();  // drains DMA for [cur]; frees [cur^1]
        if (kti + 1 < hic) {
            const _Float16* p0 = kvb + (size_t)(kti + 1) * 8192 + soff;
            glds16(p0, &kt[cur ^ 1][soff]);
            glds16(p0 + 2048, &kt[cur ^ 1][2048 + soff]);
            glds16(p0 + 4096, &vt[cur ^ 1][soff]);
            glds16(p0 + 6144, &vt[cur ^ 1][2048 + soff]);
        }

        bool diag = (kti >= 2 * qt);
        int qrel = qrow - kti * 64;                      // per-lane
        int wmax = qt * QT + wave * 32 + 31 - kti * 64;  // wave-uniform

#pragma unroll
        for (int ctk = 0; ctk < 2; ctk++) {
            if (diag && ctk * 32 > wmax) continue;  // whole 32-key block masked

            f32x16 s;
#pragma unroll
            for (int i = 0; i < 16; i++) s[i] = 0.f;
            __builtin_amdgcn_s_setprio(1);
#pragma unroll
            for (int ss = 0; ss < 4; ss++) {
                half8 ak = *(half8*)&kt[cur][kimg(ctk * 32 + l32,
                                                  ss * 16 + hi * 8)];
                s = MFMA32(ak, aq[ss], s);
            }
            __builtin_amdgcn_s_setprio(0);

            // softmax: e = exp2(s), causal mask, row-partial into l_acc
            float e[16];
#pragma unroll
            for (int r = 0; r < 16; r++) {
                float ev = __builtin_amdgcn_exp2f(s[r]);
                if (diag) {
                    int key = ctk * 32 + (r & 3) + 8 * (r >> 2) + 4 * hi;
                    if (key > qrel) ev = 0.f;
                }
                e[r] = ev;
                l_acc += ev;
            }

            // pack pairs (key even, key+1) -> pk dwords
            unsigned pk[8];
#pragma unroll
            for (int p = 0; p < 8; p++) {
                auto h2 = __builtin_amdgcn_cvt_pkrtz(e[2 * p], e[2 * p + 1]);
                union { decltype(h2) h; unsigned u; } cv;
                cv.h = h2;
                pk[p] = cv.u;
            }
            // permlane32_swap(vdst, vsrc): vdst[32:63] <-> vsrc[0:31].
            // swap(p, p+2): p-slot -> A.dw[d] (lo-half source),
            //               (p+2)-slot -> A.dw[d+2] (hi-half source).
            asm("v_permlane32_swap_b32 %0, %1" : "+v"(pk[0]), "+v"(pk[2]));
            asm("v_permlane32_swap_b32 %0, %1" : "+v"(pk[1]), "+v"(pk[3]));
            asm("v_permlane32_swap_b32 %0, %1" : "+v"(pk[4]), "+v"(pk[6]));
            asm("v_permlane32_swap_b32 %0, %1" : "+v"(pk[5]), "+v"(pk[7]));
            union { unsigned u[4]; half8 h; } A0, A1;
            A0.u[0] = pk[0]; A0.u[1] = pk[1]; A0.u[2] = pk[2]; A0.u[3] = pk[3];
            A1.u[0] = pk[4]; A1.u[1] = pk[5]; A1.u[2] = pk[6]; A1.u[3] = pk[7];

            __builtin_amdgcn_s_setprio(1);
#pragma unroll
            for (int cth = 0; cth < 2; cth++) {
                int h = cth * 32 + l32;
                half8 v0 = *(half8*)&vt[cur][vimg((2 * ctk + 0) * 16 + hi * 8, h)];
                half8 v1 = *(half8*)&vt[cur][vimg((2 * ctk + 1) * 16 + hi * 8, h)];
                o[cth] = MFMA32(A0.h, v0, o[cth]);
                o[cth] = MFMA32(A1.h, v1, o[cth]);
            }
            __builtin_amdgcn_s_setprio(0);
        }
    }

    // row sum lives split across hi halves only
    l_acc += __shfl_xor(l_acc, 32);
    float inv = l_acc > 0.f ? 1.f / l_acc : 0.f;
    if (!hi) ls[wave][l32] = inv;  // q-local -> inv, per-wave private

    if (nc == 1) {
        // single-chunk group (qt<=1): write final fp32 output directly
        float* ob = out + ((size_t)(b * TSZ + qt * QT)) * 64;
#pragma unroll
        for (int r = 0; r < 16; r++) {
            int rl = (r & 3) + 8 * (r >> 2) + 4 * hi;
            float invr = ls[wave][rl];
            int lrow = wave * 32 + rl;
            ob[lrow * 64 + l32] = o[0][r] * invr;
            ob[lrow * 64 + 32 + l32] = o[1][r] * invr;
        }
        return;
    }

    _Float16* op = opart + (size_t)part * (QT * 64);
#pragma unroll
    for (int r = 0; r < 16; r++) {
        int rl = (r & 3) + 8 * (r >> 2) + 4 * hi;  // q row of this acc reg
        float invr = ls[wave][rl];
        int lrow = wave * 32 + rl;
        op[lrow * 64 + l32] = (_Float16)(o[0][r] * invr);
        op[lrow * 64 + 32 + l32] = (_Float16)(o[1][r] * invr);
    }
    if (!hi) ml[part * QT + wave * 32 + l32] = l_acc;
}

// ---------------------------------------------------------------------------
// Kernel 4: combine nc(qt)=ceil(2(qt+1)/5) partials per row.
// Grid 512: 32 rows/block, 8 threads/row. XCD-pair swizzle matches attn's
// writer mapping so opart/ml reads are L2-local. nc==1 rows were written
// directly by attn -> early exit.
// ---------------------------------------------------------------------------
__global__ __launch_bounds__(256) void combine(
    const _Float16* __restrict__ opart, const float* __restrict__ ml,
    float* __restrict__ out) {
    int tid = threadIdx.x;
    int id = blockIdx.x;
    int xcd = id & 7;
    int b = xcd >> 1;
    int rb = (id >> 3) * 2 + (xcd & 1);  // 0..127: row-block within batch
    int row = b * TSZ + rb * 32 + (tid >> 3);
    int seg = (tid & 7) * 8;
    int qt = (row >> 7) & (NQT - 1);
    int nc = (2 * qt + 6) / 5;
    if (nc == 1) return;  // attn wrote these rows directly
    int prow = row & (QT - 1);
    int pbase = (b * NQT + qt) * MAXC;

    float acc[8];
#pragma unroll
    for (int i = 0; i < 8; i++) acc[i] = 0.f;
    float lsum = 0.f;
    for (int s = 0; s < nc; s++) {
        float l = ml[(pbase + s) * QT + prow];
        lsum += l;
        half8 h = *(const half8*)&opart[(size_t)(pbase + s) * (QT * 64) +
                                        prow * 64 + seg];
#pragma unroll
        for (int i = 0; i < 8; i++) acc[i] += l * (float)h[i];
    }
    float inv = 1.f / lsum;
    float* ob = out + (size_t)row * 64 + seg;
#pragma unroll
    for (int i = 0; i < 8; i++) ob[i] = acc[i] * inv;
}

// ---------------------------------------------------------------------------
extern "C" void kernel_launch(void* const* d_in, const int* in_sizes, int n_in,
                              void* d_out, int out_size, void* d_ws,
                              size_t ws_size, hipStream_t stream) {
    (void)in_sizes; (void)n_in; (void)out_size; (void)ws_size;
    const float* x = (const float*)d_in[0];
    const float* Wk = (const float*)d_in[1];
    const float* Wq = (const float*)d_in[2];
    const float* Wv = (const float*)d_in[3];

    _Float16* Wt = (_Float16*)d_ws;                       // 192*1024
    _Float16* qbf = Wt + 192 * 1024;                      // MSZ*64
    _Float16* kvs = qbf + (size_t)MSZ * 64;               // 256 tiles * 8192
    _Float16* opart = kvs + (size_t)MSZ * 128;            // 2048 * 8192
    float* ml = (float*)(opart + (size_t)BSZ * NQT * MAXC * QT * 64);

    wconv<<<1024, 192, 0, stream>>>(Wk, Wq, Wv, Wt);
    qkv_proj<<<MSZ / 64, 512, 0, stream>>>(x, Wt, qbf, kvs);
    attn_partial<<<BSZ * CPB, 256, 0, stream>>>(qbf, kvs, opart, ml,
                                                (float*)d_out);
    combine<<<MSZ / 32, 256, 0, stream>>>(opart, ml, (float*)d_out);
}